// Round 7
// baseline (226.966 us; speedup 1.0000x reference)
//
#include <hip/hip_runtime.h>
#include <stdint.h>

#define Bn 4
#define Cn 256
#define Gn 32
#define Nn 4096
#define CGn 8

typedef unsigned short u16;
typedef __attribute__((ext_vector_type(8))) short short8;
typedef __attribute__((ext_vector_type(4))) short short4v;
typedef __attribute__((ext_vector_type(4))) float f32x4;
typedef __attribute__((ext_vector_type(16))) float f32x16;

__device__ __forceinline__ u16 f2bf(float x) {
  uint32_t u = __float_as_uint(x);
  u += 0x7fffu + ((u >> 16) & 1u);
  return (u16)(u >> 16);
}
__device__ __forceinline__ float b2f(u16 v) {
  return __uint_as_float(((uint32_t)v) << 16);
}

// async global->LDS, 16B per lane; lds base must be wave-uniform
__device__ __forceinline__ void gl_lds16(const void* g, void* l) {
  __builtin_amdgcn_global_load_lds(
      (__attribute__((address_space(1))) void*)(uintptr_t)g,
      (__attribute__((address_space(3))) void*)(uintptr_t)l, 16, 0, 0);
}

// XOR-swizzled tile addressing (qkv/proj GEMMs): rows of 512B (32 x 16B chunks)
__device__ __forceinline__ int sw512(int row, int cb) { return row * 512 + ((cb ^ (row & 7)) * 16); }

// ---------------- fused weight-convert + GN stats ----------------------------
__global__ void k_cs(const float* __restrict__ wq, const float* __restrict__ wk,
                     const float* __restrict__ wv, const float* __restrict__ wp,
                     const float* __restrict__ bq, const float* __restrict__ bk,
                     const float* __restrict__ bv, const float* __restrict__ x,
                     u16* __restrict__ wqkv, u16* __restrict__ wpb,
                     float* __restrict__ bqkv, float* __restrict__ stats) {
  if (blockIdx.x < 256) {
    const float s = 0.09016844005556021f;  // log2(e) / sqrt(256)
    int i = blockIdx.x * 256 + threadIdx.x;
    wqkv[i]          = f2bf(wq[i] * s);
    wqkv[i + 65536]  = f2bf(wk[i]);
    wqkv[i + 131072] = f2bf(wv[i]);
    wpb[i]           = f2bf(wp[i]);
    if (i < 256) { bqkv[i] = bq[i] * s; bqkv[i + 256] = bk[i]; bqkv[i + 512] = bv[i]; }
  } else {
    int blk = blockIdx.x - 256;     // (b*32+g)*4 + part
    int grp = blk >> 2, part = blk & 3;
    const float4* base = (const float4*)(x + (size_t)grp * (CGn * Nn) + part * 8192);
    float s = 0.f, s2 = 0.f;
    for (int i = threadIdx.x; i < 2048; i += 256) {
      float4 v = base[i];
      s  += v.x + v.y + v.z + v.w;
      s2 += v.x * v.x + v.y * v.y + v.z * v.z + v.w * v.w;
    }
#pragma unroll
    for (int m = 1; m < 64; m <<= 1) { s += __shfl_xor(s, m, 64); s2 += __shfl_xor(s2, m, 64); }
    __shared__ float ps[4], ps2[4];
    int w = threadIdx.x >> 6;
    if ((threadIdx.x & 63) == 0) { ps[w] = s; ps2[w] = s2; }
    __syncthreads();
    if (threadIdx.x == 0) {
      stats[grp * 8 + part * 2]     = ps[0] + ps[1] + ps[2] + ps[3];
      stats[grp * 8 + part * 2 + 1] = ps2[0] + ps2[1] + ps2[2] + ps2[3];
    }
  }
}

// ---------------- GN apply -> hnT (N,C) bf16, coalesced via LDS transpose ----
__global__ void k_apply(const float* __restrict__ x, const float* __restrict__ stats,
                        const float* __restrict__ gsc, const float* __restrict__ gbi,
                        u16* __restrict__ hnT) {
  __shared__ __align__(16) char smem[32768];  // 64 n-rows x 512B (c), rotated
  __shared__ float smu[Gn], srs[Gn];
  int n0 = blockIdx.x * 64;
  int b = blockIdx.y;
  int tid = threadIdx.x;
  if (tid < Gn) {
    float S = 0.f, S2 = 0.f;
#pragma unroll
    for (int p = 0; p < 4; ++p) {
      S  += stats[(b * Gn + tid) * 8 + p * 2];
      S2 += stats[(b * Gn + tid) * 8 + p * 2 + 1];
    }
    const float inv = 1.f / (CGn * Nn);
    float mu = S * inv;
    float var = S2 * inv - mu * mu;
    smu[tid] = mu;
    srs[tid] = rsqrtf(var + 1e-6f);
  }
  __syncthreads();
  int nl = (tid & 15) * 4;
  int cbase = tid >> 4;
  for (int pass = 0; pass < 16; ++pass) {
    int c = pass * 16 + cbase;
    float4 v = *(const float4*)(x + (size_t)b * Cn * Nn + (size_t)c * Nn + n0 + nl);
    int g = c >> 3;
    float sc = gsc[c] * srs[g];
    float bi = gbi[c] - smu[g] * sc;
    float vals[4] = {v.x, v.y, v.z, v.w};
#pragma unroll
    for (int i = 0; i < 4; ++i) {
      int row = nl + i;
      int off = row * 512 + ((((c >> 3) + row) & 31) * 16) + (c & 7) * 2;
      *(u16*)(smem + off) = f2bf(vals[i] * sc + bi);
    }
  }
  __syncthreads();
#pragma unroll
  for (int p = 0; p < 8; ++p) {
    int idx = p * 256 + tid;   // 2048 chunk-slots
    int row = idx >> 5, pc = idx & 31;
    int gc = (pc - row) & 31;
    short8 v8 = *(const short8*)(smem + row * 512 + pc * 16);
    *(short8*)(hnT + ((size_t)b * Nn + n0 + row) * Cn + gc * 8) = v8;
  }
}

// ---------------- fused QKV GEMM: out[d,n] = sum_c W[d,c] hn[c,n] + bias ------
__global__ __launch_bounds__(256, 2)
void k_qkv(const u16* __restrict__ wqkv, const float* __restrict__ bqkv,
           const u16* __restrict__ hnT, u16* __restrict__ qT, u16* __restrict__ kT,
           u16* __restrict__ vv) {
  __shared__ __align__(16) char smem[65536];  // Ws [64][512B sw] | hns [64][512B sw]
  int tid = threadIdx.x, lane = tid & 63, w = tid >> 6, quad = lane >> 4, low = lane & 15;
  int n0 = blockIdx.x * 64, d0 = blockIdx.y * 64, b = blockIdx.z;
  {
    int r0 = w * 16;
#pragma unroll
    for (int s = 0; s < 8; ++s) {
      int rs = r0 + s * 2;
      int r = rs + (lane >> 5);
      int cb = (lane & 31) ^ (r & 7);
      gl_lds16(wqkv + (size_t)(d0 + r) * Cn + cb * 8, smem + rs * 512);
      gl_lds16(hnT + ((size_t)b * Nn + n0 + r) * Cn + cb * 8, smem + 32768 + rs * 512);
    }
  }
  asm volatile("s_waitcnt vmcnt(0)" ::: "memory");
  __syncthreads();
  f32x4 acc[4] = {{0.f,0.f,0.f,0.f},{0.f,0.f,0.f,0.f},{0.f,0.f,0.f,0.f},{0.f,0.f,0.f,0.f}};
#pragma unroll
  for (int kk = 0; kk < 8; ++kk) {
    short8 af = *(const short8*)(smem + sw512(w * 16 + low, kk * 4 + quad));
#pragma unroll
    for (int t = 0; t < 4; ++t) {
      short8 bf = *(const short8*)(smem + 32768 + sw512(t * 16 + low, kk * 4 + quad));
      acc[t] = __builtin_amdgcn_mfma_f32_16x16x32_bf16(af, bf, acc[t], 0, 0, 0);
    }
  }
  int which = d0 >> 8;
  float bias[4];
#pragma unroll
  for (int r = 0; r < 4; ++r) bias[r] = bqkv[d0 + w * 16 + quad * 4 + r];
  __syncthreads();  // all waves done reading GEMM tiles; reuse smem[0..8K)
  if (which == 2) {
#pragma unroll
    for (int t = 0; t < 4; ++t)
#pragma unroll
      for (int r = 0; r < 4; ++r) {
        int row = w * 16 + quad * 4 + r;   // d_local
        int col = t * 16 + low;            // n_local
        int off = row * 128 + ((((col >> 3) ^ ((row >> 1) & 7)) & 7) * 16) + (col & 7) * 2;
        *(u16*)(smem + off) = f2bf(acc[t][r] + bias[r]);
      }
  } else {
#pragma unroll
    for (int t = 0; t < 4; ++t)
#pragma unroll
      for (int r = 0; r < 4; ++r) {
        int row = t * 16 + low;            // n_local
        int col = w * 16 + quad * 4 + r;   // d_local
        int off = row * 128 + ((((col >> 3) ^ ((row >> 1) & 7)) & 7) * 16) + (col & 7) * 2;
        *(u16*)(smem + off) = f2bf(acc[t][r] + bias[r]);
      }
  }
  __syncthreads();
  int dl0 = d0 & 255;
#pragma unroll
  for (int p = 0; p < 2; ++p) {
    int idx = p * 256 + tid;       // [0,512) chunk-slots
    int row = idx >> 3, pc = idx & 7;
    int cb = pc ^ ((row >> 1) & 7);
    short8 v8 = *(const short8*)(smem + row * 128 + pc * 16);
    if (which == 2)
      *(short8*)(vv + (size_t)b * Cn * Nn + (size_t)(dl0 + row) * Nn + n0 + cb * 8) = v8;
    else {
      u16* dst = (which == 0 ? qT : kT) + (size_t)b * Nn * Cn;
      *(short8*)(dst + (size_t)(n0 + row) * Cn + dl0 + cb * 8) = v8;
    }
  }
}

// ---------------- flash attention: pipelined P-carry K-loop ------------------
// Body(t): PV(t-1) -> BAR -> stage(t+1) -> vmcnt(8) -> BAR -> S(t) -> exp/P(t).
// PV's 16 independent MFMAs + staging DMA overlap the dependent S-chain; S is
// split into 2 accumulator chains. P packed via v_perm (1 op per bf16 pair).
__device__ __forceinline__ void flash_stage(char* smem, int bsel, const u16* kTb,
                                            const u16* vb, int j0, int w, int lo,
                                            int kr, int vr, int vp) {
  char* ksb = smem + bsel * 32768;
  char* vsb = ksb + 16384;
#pragma unroll
  for (int s = 0; s < 4; ++s) {   // ks: 32 rows x 512B, row-rotated chunks
    int j = kr + s * 2;
    int gc = (lo - j) & 31;
    gl_lds16(kTb + (size_t)(j0 + j) * Cn + gc * 8, ksb + (w * 8 + s * 2) * 512);
  }
#pragma unroll
  for (int s = 0; s < 4; ++s) {   // vs: 256 rows x 64B, rot(c)=c+(c>>2)
    int c = vr + s * 16;
    int gc = (vp - c - (c >> 2)) & 3;
    gl_lds16(vb + (size_t)c * Nn + j0 + gc * 8, vsb + (w * 64 + s * 16) * 64);
  }
}

__global__ __launch_bounds__(256, 2)
void k_flash(const u16* __restrict__ qT, const u16* __restrict__ kT,
             const u16* __restrict__ vv, u16* __restrict__ Op0,
             u16* __restrict__ Op1, u16* __restrict__ Op2, u16* __restrict__ Op3,
             float* __restrict__ lrow) {
  __shared__ __align__(16) char smem[65536];
  const int tid = threadIdx.x, lane = tid & 63, w = tid >> 6;
  const int lo = lane & 31, hi = lane >> 5;
  const int i0 = blockIdx.x * 128;
  const int b = blockIdx.y, jh = blockIdx.z;
  const u16* qTb = qT + (size_t)b * Nn * Cn;
  const u16* kTb = kT + (size_t)b * Nn * Cn;
  const u16* vb  = vv + (size_t)b * Cn * Nn;
  const int u7 = lo + hi;
  const int u9 = lo + hi + (lo >> 2);   // vs read rotation
  const int kr = w * 8 + hi;
  const int vr = w * 64 + (lane >> 2);
  const int vp = lane & 3;

  flash_stage(smem, 0, kTb, vb, jh * 1024, w, lo, kr, vr, vp);

  // q B-frags: lane holds q[i = i0+w*32+lo][c = ks*16 + hi*8 + e]
  short8 qf[16];
  {
    const u16* qrow = qTb + (size_t)(i0 + w * 32 + lo) * Cn + hi * 8;
#pragma unroll
    for (int ks = 0; ks < 16; ++ks) qf[ks] = *(const short8*)(qrow + ks * 16);
  }
  f32x16 Oa[8];
#pragma unroll
  for (int ct = 0; ct < 8; ++ct)
#pragma unroll
    for (int e = 0; e < 16; ++e) Oa[ct][e] = 0.f;
  float l_ = 0.f;
  uint32_t Pp[8];

  for (int jt = 0; jt < 32; ++jt) {
    if (jt > 0) {
      // PV(jt-1): vs buffer parity (jt-1)&1 == (jt+1)&1
      const char* vsb = smem + ((jt + 1) & 1) * 32768 + 16384;
#pragma unroll
      for (int kst = 0; kst < 2; ++kst) {
        uint32_t a0 = Pp[4 * kst], a1 = Pp[4 * kst + 1];
        uint32_t b0 = Pp[4 * kst + 2], b1 = Pp[4 * kst + 3];
        uint32_t s0 = hi ? a0 : b0, s1 = hi ? a1 : b1;
        uint32_t r0 = (uint32_t)__shfl_xor((int)s0, 32, 64);
        uint32_t r1 = (uint32_t)__shfl_xor((int)s1, 32, 64);
        union { uint32_t u[4]; short8 s8; } pu;
        pu.u[0] = hi ? r0 : a0;
        pu.u[1] = hi ? r1 : a1;
        pu.u[2] = hi ? b0 : r0;
        pu.u[3] = hi ? b1 : r1;
        int ch = (kst * 2 + u9) & 3;
#pragma unroll
        for (int ct = 0; ct < 8; ++ct) {
          short8 vf = *(const short8*)(vsb + (ct * 32 + lo) * 64 + ch * 16);
          Oa[ct] = __builtin_amdgcn_mfma_f32_32x32x16_bf16(vf, pu.s8, Oa[ct], 0, 0, 0);
        }
      }
    }
    asm volatile("s_barrier" ::: "memory");   // BAR_A: vs(t-1)/ks(t-1) readers done
    if (jt < 31) {
      flash_stage(smem, (jt + 1) & 1, kTb, vb, jh * 1024 + (jt + 1) * 32, w, lo, kr, vr, vp);
      asm volatile("s_waitcnt vmcnt(8)" ::: "memory");  // stage(t) landed (mine)
    } else {
      asm volatile("s_waitcnt vmcnt(0)" ::: "memory");
    }
    asm volatile("s_barrier" ::: "memory");   // BAR_B: stage(t) landed block-wide
    const char* ksb = smem + (jt & 1) * 32768;

    // S^T = K·q : two independent accumulator chains
    f32x16 Sa, Sb;
#pragma unroll
    for (int e = 0; e < 16; ++e) { Sa[e] = 0.f; Sb[e] = 0.f; }
#pragma unroll
    for (int ks = 0; ks < 16; ks += 2) {
      int ch0 = (ks * 2 + u7) & 31;
      int ch1 = (ks * 2 + 2 + u7) & 31;
      short8 a0 = *(const short8*)(ksb + lo * 512 + ch0 * 16);
      short8 a1 = *(const short8*)(ksb + lo * 512 + ch1 * 16);
      Sa = __builtin_amdgcn_mfma_f32_32x32x16_bf16(a0, qf[ks], Sa, 0, 0, 0);
      Sb = __builtin_amdgcn_mfma_f32_32x32x16_bf16(a1, qf[ks + 1], Sb, 0, 0, 0);
    }
    // P = exp2(Sa+Sb); pack bf16 pairs via v_perm; per-lane l
#pragma unroll
    for (int g = 0; g < 8; ++g) {
      float p0 = __builtin_amdgcn_exp2f(Sa[2 * g] + Sb[2 * g]);
      float p1 = __builtin_amdgcn_exp2f(Sa[2 * g + 1] + Sb[2 * g + 1]);
      l_ += p0 + p1;
      Pp[g] = __builtin_amdgcn_perm(__float_as_uint(p1), __float_as_uint(p0), 0x07060302u);
    }
  }
  // epilogue PV(31): vs buffer parity 31&1 = 1
  {
    const char* vsb = smem + 32768 + 16384;
#pragma unroll
    for (int kst = 0; kst < 2; ++kst) {
      uint32_t a0 = Pp[4 * kst], a1 = Pp[4 * kst + 1];
      uint32_t b0 = Pp[4 * kst + 2], b1 = Pp[4 * kst + 3];
      uint32_t s0 = hi ? a0 : b0, s1 = hi ? a1 : b1;
      uint32_t r0 = (uint32_t)__shfl_xor((int)s0, 32, 64);
      uint32_t r1 = (uint32_t)__shfl_xor((int)s1, 32, 64);
      union { uint32_t u[4]; short8 s8; } pu;
      pu.u[0] = hi ? r0 : a0;
      pu.u[1] = hi ? r1 : a1;
      pu.u[2] = hi ? b0 : r0;
      pu.u[3] = hi ? b1 : r1;
      int ch = (kst * 2 + u9) & 3;
#pragma unroll
      for (int ct = 0; ct < 8; ++ct) {
        short8 vf = *(const short8*)(vsb + (ct * 32 + lo) * 64 + ch * 16);
        Oa[ct] = __builtin_amdgcn_mfma_f32_32x32x16_bf16(vf, pu.s8, Oa[ct], 0, 0, 0);
      }
    }
  }

  // l: lane pair holds complementary j halves
  l_ += __shfl_xor(l_, 32, 64);
  if (hi == 0)
    lrow[(size_t)jh * (Bn * Nn) + (size_t)b * Nn + i0 + w * 32 + lo] = l_;
  float invl = __builtin_amdgcn_rcpf(l_);
  __syncthreads();  // all waves done with ks/vs; reuse all 64KB
#pragma unroll
  for (int ct = 0; ct < 8; ++ct)
#pragma unroll
    for (int g = 0; g < 4; ++g) {
      short4v pk;
#pragma unroll
      for (int r = 0; r < 4; ++r) pk[r] = (short)f2bf(Oa[ct][g * 4 + r] * invl);
      int chv = (ct * 4 + g + lo) & 31;
      *(short4v*)(smem + w * 16384 + lo * 512 + chv * 16 + hi * 8) = pk;
    }
  __syncthreads();
  u16* Opj = (jh == 0) ? Op0 : (jh == 1) ? Op1 : (jh == 2) ? Op2 : Op3;
  u16* Ob = Opj + ((size_t)b * Nn + i0 + w * 32) * (size_t)Cn;
#pragma unroll
  for (int s = 0; s < 16; ++s) {
    int rr = s * 2 + hi;
    short8 v8 = *(const short8*)(smem + w * 16384 + rr * 512 + lo * 16);
    int gc = (lo - rr) & 31;
    *(short8*)(Ob + (size_t)rr * Cn + gc * 8) = v8;
  }
}

// ---------------- combine the 4 KV partials -> OT (N,C) bf16 -----------------
__global__ void k_comb(const u16* __restrict__ O0, const u16* __restrict__ O1,
                       const u16* __restrict__ O2, const u16* __restrict__ O3,
                       const float* __restrict__ lrow, u16* __restrict__ OT) {
  int gid = blockIdx.x * 256 + threadIdx.x;  // 1M threads, 4 cols each
  int row = gid >> 6;
  int c4 = (gid & 63) << 2;
  float L = lrow[row] + lrow[Bn * Nn + row] + lrow[2 * Bn * Nn + row] + lrow[3 * Bn * Nn + row];
  float inv = __builtin_amdgcn_rcpf(L);
  size_t base = (size_t)row * Cn + c4;
  short4v a0 = *(const short4v*)(O0 + base);
  short4v a1 = *(const short4v*)(O1 + base);
  short4v a2 = *(const short4v*)(O2 + base);
  short4v a3 = *(const short4v*)(O3 + base);
  short4v o;
#pragma unroll
  for (int i = 0; i < 4; ++i)
    o[i] = (short)f2bf((b2f((u16)a0[i]) + b2f((u16)a1[i]) + b2f((u16)a2[i]) + b2f((u16)a3[i])) * inv);
  *(short4v*)(OT + base) = o;
}

// ---------------- proj GEMM + bias + residual --------------------------------
__global__ __launch_bounds__(256, 2)
void k_proj(const u16* __restrict__ wpb, const float* __restrict__ bp,
            const u16* __restrict__ OT, const float* __restrict__ x,
            float* __restrict__ out) {
  __shared__ __align__(16) char smem[65536];
  int tid = threadIdx.x, lane = tid & 63, w = tid >> 6, quad = lane >> 4, low = lane & 15;
  int n0 = blockIdx.x * 64, d0 = blockIdx.y * 64, b = blockIdx.z;
  {
    int r0 = w * 16;
#pragma unroll
    for (int s = 0; s < 8; ++s) {
      int rs = r0 + s * 2;
      int r = rs + (lane >> 5);
      int cb = (lane & 31) ^ (r & 7);
      gl_lds16(wpb + (size_t)(d0 + r) * Cn + cb * 8, smem + rs * 512);
      gl_lds16(OT + ((size_t)b * Nn + n0 + r) * Cn + cb * 8, smem + 32768 + rs * 512);
    }
  }
  asm volatile("s_waitcnt vmcnt(0)" ::: "memory");
  __syncthreads();
  f32x4 acc[4] = {{0.f,0.f,0.f,0.f},{0.f,0.f,0.f,0.f},{0.f,0.f,0.f,0.f},{0.f,0.f,0.f,0.f}};
#pragma unroll
  for (int kk = 0; kk < 8; ++kk) {
    short8 af = *(const short8*)(smem + sw512(w * 16 + low, kk * 4 + quad));
#pragma unroll
    for (int t = 0; t < 4; ++t) {
      short8 bf = *(const short8*)(smem + 32768 + sw512(t * 16 + low, kk * 4 + quad));
      acc[t] = __builtin_amdgcn_mfma_f32_16x16x32_bf16(af, bf, acc[t], 0, 0, 0);
    }
  }
  int dloc = d0 + w * 16 + quad * 4;
#pragma unroll
  for (int t = 0; t < 4; ++t)
#pragma unroll
    for (int r = 0; r < 4; ++r) {
      size_t idx = (size_t)b * Cn * Nn + (size_t)(dloc + r) * Nn + n0 + t * 16 + low;
      out[idx] = x[idx] + acc[t][r] + bp[dloc + r];
    }
}

// ---------------- launcher ----------------------------------------------------
extern "C" void kernel_launch(void* const* d_in, const int* in_sizes, int n_in,
                              void* d_out, int out_size, void* d_ws, size_t ws_size,
                              hipStream_t stream) {
  const float* x   = (const float*)d_in[0];
  const float* gsc = (const float*)d_in[1];
  const float* gbi = (const float*)d_in[2];
  const float* wq  = (const float*)d_in[3];
  const float* bq  = (const float*)d_in[4];
  const float* wk  = (const float*)d_in[5];
  const float* bk  = (const float*)d_in[6];
  const float* wv  = (const float*)d_in[7];
  const float* bv  = (const float*)d_in[8];
  const float* wp  = (const float*)d_in[9];
  const float* bp  = (const float*)d_in[10];
  float* out = (float*)d_out;

  char* ws = (char*)d_ws;
  u16*   wqkv  = (u16*)(ws + 0);          // 384 KB
  u16*   wpb   = (u16*)(ws + 393216);     // 128 KB
  float* bqkv  = (float*)(ws + 524288);   // 3 KB
  float* stats = (float*)(ws + 527360);   // 4 KB (per-part slots)
  float* lrow  = (float*)(ws + 532480);   // 256 KB
  u16*   hnT   = (u16*)(ws + 1048576);    // 8 MB; reused as Op0 after qkv
  u16*   qT    = (u16*)(ws + 9437184);    // 8 MB; reused as OT after flash
  u16*   kT    = (u16*)(ws + 17825792);   // 8 MB
  u16*   vv    = (u16*)(ws + 26214400);   // 8 MB
  u16*   Op1   = (u16*)(ws + 34603008);   // 8 MB
  u16*   Op2   = (u16*)(ws + 42991616);   // 8 MB
  u16*   Op3   = (u16*)(ws + 51380224);   // 8 MB; end ~57 MB

  k_cs<<<768, 256, 0, stream>>>(wq, wk, wv, wp, bq, bk, bv, x, wqkv, wpb, bqkv, stats);
  k_apply<<<dim3(64, 4), 256, 0, stream>>>(x, stats, gsc, gbi, hnT);
  k_qkv<<<dim3(64, 12, 4), 256, 0, stream>>>(wqkv, bqkv, hnT, qT, kT, vv);
  k_flash<<<dim3(32, 4, 4), 256, 0, stream>>>(qT, kT, vv, hnT /*Op0*/, Op1, Op2, Op3, lrow);
  k_comb<<<4096, 256, 0, stream>>>(hnT, Op1, Op2, Op3, lrow, qT /*OT*/);
  k_proj<<<dim3(64, 4, 4), 256, 0, stream>>>(wpb, bp, qT /*OT*/, x, out);
}

// Round 8
// 201.046 us; speedup vs baseline: 1.1289x; 1.1289x over previous
//
#include <hip/hip_runtime.h>
#include <stdint.h>

#define Bn 4
#define Cn 256
#define Gn 32
#define Nn 4096
#define CGn 8

typedef unsigned short u16;
typedef __attribute__((ext_vector_type(8))) short short8;
typedef __attribute__((ext_vector_type(4))) short short4v;
typedef __attribute__((ext_vector_type(4))) float f32x4;
typedef __attribute__((ext_vector_type(16))) float f32x16;

__device__ __forceinline__ u16 f2bf(float x) {
  uint32_t u = __float_as_uint(x);
  u += 0x7fffu + ((u >> 16) & 1u);
  return (u16)(u >> 16);
}
__device__ __forceinline__ float b2f(u16 v) {
  return __uint_as_float(((uint32_t)v) << 16);
}

// async global->LDS, 16B per lane; lds base must be wave-uniform
__device__ __forceinline__ void gl_lds16(const void* g, void* l) {
  __builtin_amdgcn_global_load_lds(
      (__attribute__((address_space(1))) void*)(uintptr_t)g,
      (__attribute__((address_space(3))) void*)(uintptr_t)l, 16, 0, 0);
}

// XOR-swizzled tile addressing (proj GEMM): rows of 512B (32 x 16B chunks)
__device__ __forceinline__ int sw512(int row, int cb) { return row * 512 + ((cb ^ (row & 7)) * 16); }

// ---------------- fused weight-convert + GN stats ----------------------------
__global__ void k_cs(const float* __restrict__ wq, const float* __restrict__ wk,
                     const float* __restrict__ wv, const float* __restrict__ wp,
                     const float* __restrict__ bq, const float* __restrict__ bk,
                     const float* __restrict__ bv, const float* __restrict__ x,
                     u16* __restrict__ wqkv, u16* __restrict__ wpb,
                     float* __restrict__ bqkv, float* __restrict__ stats) {
  if (blockIdx.x < 256) {
    const float s = 0.09016844005556021f;  // log2(e) / sqrt(256)
    int i = blockIdx.x * 256 + threadIdx.x;
    wqkv[i]          = f2bf(wq[i] * s);
    wqkv[i + 65536]  = f2bf(wk[i]);
    wqkv[i + 131072] = f2bf(wv[i]);
    wpb[i]           = f2bf(wp[i]);
    if (i < 256) { bqkv[i] = bq[i] * s; bqkv[i + 256] = bk[i]; bqkv[i + 512] = bv[i]; }
  } else {
    int blk = blockIdx.x - 256;     // (b*32+g)*4 + part
    int grp = blk >> 2, part = blk & 3;
    const float4* base = (const float4*)(x + (size_t)grp * (CGn * Nn) + part * 8192);
    float s = 0.f, s2 = 0.f;
    for (int i = threadIdx.x; i < 2048; i += 256) {
      float4 v = base[i];
      s  += v.x + v.y + v.z + v.w;
      s2 += v.x * v.x + v.y * v.y + v.z * v.z + v.w * v.w;
    }
#pragma unroll
    for (int m = 1; m < 64; m <<= 1) { s += __shfl_xor(s, m, 64); s2 += __shfl_xor(s2, m, 64); }
    __shared__ float ps[4], ps2[4];
    int w = threadIdx.x >> 6;
    if ((threadIdx.x & 63) == 0) { ps[w] = s; ps2[w] = s2; }
    __syncthreads();
    if (threadIdx.x == 0) {
      stats[grp * 8 + part * 2]     = ps[0] + ps[1] + ps[2] + ps[3];
      stats[grp * 8 + part * 2 + 1] = ps2[0] + ps2[1] + ps2[2] + ps2[3];
    }
  }
}

// ---------------- GN apply -> hnT (N,C) bf16, coalesced via LDS transpose ----
__global__ void k_apply(const float* __restrict__ x, const float* __restrict__ stats,
                        const float* __restrict__ gsc, const float* __restrict__ gbi,
                        u16* __restrict__ hnT) {
  __shared__ __align__(16) char smem[32768];  // 64 n-rows x 512B (c), rotated
  __shared__ float smu[Gn], srs[Gn];
  int n0 = blockIdx.x * 64;
  int b = blockIdx.y;
  int tid = threadIdx.x;
  if (tid < Gn) {
    float S = 0.f, S2 = 0.f;
#pragma unroll
    for (int p = 0; p < 4; ++p) {
      S  += stats[(b * Gn + tid) * 8 + p * 2];
      S2 += stats[(b * Gn + tid) * 8 + p * 2 + 1];
    }
    const float inv = 1.f / (CGn * Nn);
    float mu = S * inv;
    float var = S2 * inv - mu * mu;
    smu[tid] = mu;
    srs[tid] = rsqrtf(var + 1e-6f);
  }
  __syncthreads();
  int nl = (tid & 15) * 4;
  int cbase = tid >> 4;
  for (int pass = 0; pass < 16; ++pass) {
    int c = pass * 16 + cbase;
    float4 v = *(const float4*)(x + (size_t)b * Cn * Nn + (size_t)c * Nn + n0 + nl);
    int g = c >> 3;
    float sc = gsc[c] * srs[g];
    float bi = gbi[c] - smu[g] * sc;
    float vals[4] = {v.x, v.y, v.z, v.w};
#pragma unroll
    for (int i = 0; i < 4; ++i) {
      int row = nl + i;
      int off = row * 512 + ((((c >> 3) + row) & 31) * 16) + (c & 7) * 2;
      *(u16*)(smem + off) = f2bf(vals[i] * sc + bi);
    }
  }
  __syncthreads();
#pragma unroll
  for (int p = 0; p < 8; ++p) {
    int idx = p * 256 + tid;   // 2048 chunk-slots
    int row = idx >> 5, pc = idx & 31;
    int gc = (pc - row) & 31;
    short8 v8 = *(const short8*)(smem + row * 512 + pc * 16);
    *(short8*)(hnT + ((size_t)b * Nn + n0 + row) * Cn + gc * 8) = v8;
  }
}

// ---------------- QKV GEMM v2: W in registers, streamed hn, pipelined --------
// Block: 64 d-rows x 256 n (4 tiles of 64), dbuf 2x32KB. Per iter:
// stage(t+1) -> vmcnt(10) -> BAR -> 32 MFMA -> BAR -> epilogue in consumed buf
// (wave-private quarter; 48B-row layout for q/k, 144B for v; 16B global stores)
__global__ __launch_bounds__(256, 2)
void k_qkv(const u16* __restrict__ wqkv, const float* __restrict__ bqkv,
           const u16* __restrict__ hnT, u16* __restrict__ qT, u16* __restrict__ kT,
           u16* __restrict__ vv) {
  __shared__ __align__(16) char smem[65536];
  const int tid = threadIdx.x, lane = tid & 63, w = tid >> 6;
  const int quad = (lane >> 4) & 3, low = lane & 15;
  const int d0 = blockIdx.y * 64, b = blockIdx.z;
  const int n_base = blockIdx.x * 256;
  const int which = d0 >> 8;
  const int dl0 = d0 & 255;
  const u16* hb = hnT + (size_t)b * Nn * Cn;
  const int scol = lane & 31;

#define QKV_STAGE(bsel, nt)                                                     \
  {                                                                             \
    _Pragma("unroll") for (int s = 0; s < 8; ++s) {                             \
      int r = w * 16 + s * 2 + (lane >> 5);                                     \
      int gc = (scol - r) & 31;                                                 \
      gl_lds16(hb + (size_t)(n_base + (nt) * 64 + r) * Cn + gc * 8,             \
               smem + (bsel) * 32768 + (w * 16 + s * 2) * 512);                 \
    }                                                                           \
  }

  QKV_STAGE(0, 0);
  // W A-frags in registers: af[kk][e] = W[d0+w*16+low][kk*32 + quad*8 + e]
  short8 af[8];
  {
    const u16* wrow = wqkv + (size_t)(d0 + w * 16 + low) * Cn + quad * 8;
#pragma unroll
    for (int kk = 0; kk < 8; ++kk) af[kk] = *(const short8*)(wrow + kk * 32);
  }
  float bias[4];
#pragma unroll
  for (int r = 0; r < 4; ++r) bias[r] = bqkv[d0 + w * 16 + quad * 4 + r];

  for (int nt = 0; nt < 4; ++nt) {
    if (nt < 3) {
      QKV_STAGE((nt + 1) & 1, nt + 1);
      asm volatile("s_waitcnt vmcnt(10)" ::: "memory");  // drain stage(nt), skip 2 ep stores + stage(nt+1)
    } else {
      asm volatile("s_waitcnt vmcnt(0)" ::: "memory");
    }
    asm volatile("s_barrier" ::: "memory");
    char* buf = smem + (nt & 1) * 32768;
    f32x4 acc[4] = {{0.f,0.f,0.f,0.f},{0.f,0.f,0.f,0.f},{0.f,0.f,0.f,0.f},{0.f,0.f,0.f,0.f}};
#pragma unroll
    for (int kk = 0; kk < 8; ++kk)
#pragma unroll
      for (int t = 0; t < 4; ++t) {
        int row = t * 16 + low;
        short8 bf = *(const short8*)(buf + row * 512 + (((kk * 4 + quad) + row) & 31) * 16);
        acc[t] = __builtin_amdgcn_mfma_f32_16x16x32_bf16(af[kk], bf, acc[t], 0, 0, 0);
      }
    asm volatile("s_barrier" ::: "memory");   // all waves done reading buf
    char* Q = buf + w * 8192;                 // wave-private scratch quarter
    if (which == 2) {
      // v: 16 d-rows x 144B (n ascending bytes 0..128)
#pragma unroll
      for (int t = 0; t < 4; ++t)
#pragma unroll
        for (int r = 0; r < 4; ++r)
          *(u16*)(Q + (quad * 4 + r) * 144 + t * 32 + low * 2) = f2bf(acc[t][r] + bias[r]);
#pragma unroll
      for (int s = 0; s < 2; ++s) {
        int slot = s * 64 + lane;
        int row = slot >> 3, ch = slot & 7;
        short8 v8 = *(const short8*)(Q + row * 144 + ch * 16);
        *(short8*)(vv + (size_t)b * Cn * Nn + (size_t)(dl0 + w * 16 + row) * Nn +
                   n_base + nt * 64 + ch * 8) = v8;
      }
    } else {
      // q/k: 64 n-rows x 48B (16 d bf16 in bytes 0..32)
#pragma unroll
      for (int t = 0; t < 4; ++t) {
        short4v pk;
#pragma unroll
        for (int r = 0; r < 4; ++r) pk[r] = (short)f2bf(acc[t][r] + bias[r]);
        *(short4v*)(Q + (t * 16 + low) * 48 + quad * 8) = pk;
      }
      u16* dst = (which == 0 ? qT : kT) + (size_t)b * Nn * Cn;
#pragma unroll
      for (int s = 0; s < 2; ++s) {
        int slot = s * 64 + lane;
        int row = slot >> 1, half = slot & 1;
        short8 v8 = *(const short8*)(Q + row * 48 + half * 16);
        *(short8*)(dst + (size_t)(n_base + nt * 64 + row) * Cn + dl0 + w * 16 + half * 8) = v8;
      }
    }
  }
#undef QKV_STAGE
}

// ---------------- flash attention, pipelined double-buffered K-loop (R6) -----
__device__ __forceinline__ void flash_stage(char* smem, int bsel, const u16* kTb,
                                            const u16* vb, int j0, int w, int lo,
                                            int kr, int vr, int vp) {
  char* ksb = smem + bsel * 32768;
  char* vsb = ksb + 16384;
#pragma unroll
  for (int s = 0; s < 4; ++s) {   // ks: 32 rows x 512B, row-rotated chunks
    int j = kr + s * 2;
    int gc = (lo - j) & 31;
    gl_lds16(kTb + (size_t)(j0 + j) * Cn + gc * 8, ksb + (w * 8 + s * 2) * 512);
  }
#pragma unroll
  for (int s = 0; s < 4; ++s) {   // vs: 256 rows x 64B, rot(c)=c+(c>>2)
    int c = vr + s * 16;
    int gc = (vp - c - (c >> 2)) & 3;
    gl_lds16(vb + (size_t)c * Nn + j0 + gc * 8, vsb + (w * 64 + s * 16) * 64);
  }
}

__global__ __launch_bounds__(256, 2)
void k_flash(const u16* __restrict__ qT, const u16* __restrict__ kT,
             const u16* __restrict__ vv, u16* __restrict__ Op0,
             u16* __restrict__ Op1, u16* __restrict__ Op2, u16* __restrict__ Op3,
             float* __restrict__ lrow) {
  __shared__ __align__(16) char smem[65536];
  const int tid = threadIdx.x, lane = tid & 63, w = tid >> 6;
  const int lo = lane & 31, hi = lane >> 5;
  const int i0 = blockIdx.x * 128;
  const int b = blockIdx.y, jh = blockIdx.z;
  const u16* qTb = qT + (size_t)b * Nn * Cn;
  const u16* kTb = kT + (size_t)b * Nn * Cn;
  const u16* vb  = vv + (size_t)b * Cn * Nn;
  const int u7 = lo + hi;
  const int u9 = lo + hi + (lo >> 2);   // vs read rotation
  const int kr = w * 8 + hi;
  const int vr = w * 64 + (lane >> 2);
  const int vp = lane & 3;

  flash_stage(smem, 0, kTb, vb, jh * 1024, w, lo, kr, vr, vp);

  // q B-frags: lane holds q[i = i0+w*32+lo][c = ks*16 + hi*8 + e]
  short8 qf[16];
  {
    const u16* qrow = qTb + (size_t)(i0 + w * 32 + lo) * Cn + hi * 8;
#pragma unroll
    for (int ks = 0; ks < 16; ++ks) qf[ks] = *(const short8*)(qrow + ks * 16);
  }
  f32x16 Oa[8];
#pragma unroll
  for (int ct = 0; ct < 8; ++ct)
#pragma unroll
    for (int e = 0; e < 16; ++e) Oa[ct][e] = 0.f;
  float l_ = 0.f;

  for (int jt = 0; jt < 32; ++jt) {
    if (jt < 31) {
      flash_stage(smem, (jt + 1) & 1, kTb, vb, jh * 1024 + (jt + 1) * 32, w, lo, kr, vr, vp);
      asm volatile("s_waitcnt vmcnt(8)" ::: "memory");   // only the older 8 (current tile)
    } else {
      asm volatile("s_waitcnt vmcnt(0)" ::: "memory");
    }
    asm volatile("s_barrier" ::: "memory");              // raw: no vmcnt(0) drain
    const char* ksb = smem + (jt & 1) * 32768;
    const char* vsb = ksb + 16384;

    // S^T = K·q : D[m=j 32][n=i 32], A = ks (rotated), B = qf
    f32x16 S0;
#pragma unroll
    for (int e = 0; e < 16; ++e) S0[e] = 0.f;
#pragma unroll
    for (int ks = 0; ks < 16; ++ks) {
      int ch = (ks * 2 + u7) & 31;
      short8 a0 = *(const short8*)(ksb + lo * 512 + ch * 16);
      S0 = __builtin_amdgcn_mfma_f32_32x32x16_bf16(a0, qf[ks], S0, 0, 0, 0);
    }
    // P = exp2(S), pack bf16 pairs, per-lane l
    uint32_t Pp[8];
#pragma unroll
    for (int g = 0; g < 8; ++g) {
      float p0 = __builtin_amdgcn_exp2f(S0[2 * g]);
      float p1 = __builtin_amdgcn_exp2f(S0[2 * g + 1]);
      l_ += p0 + p1;
      Pp[g] = ((uint32_t)f2bf(p1) << 16) | f2bf(p0);
    }
    // PV: O^T[m=c][n=i] += V·P ; P B-frag via half-lane exchange
#pragma unroll
    for (int kst = 0; kst < 2; ++kst) {
      uint32_t a0 = Pp[4 * kst], a1 = Pp[4 * kst + 1];
      uint32_t b0 = Pp[4 * kst + 2], b1 = Pp[4 * kst + 3];
      uint32_t s0 = hi ? a0 : b0, s1 = hi ? a1 : b1;
      uint32_t r0 = (uint32_t)__shfl_xor((int)s0, 32, 64);
      uint32_t r1 = (uint32_t)__shfl_xor((int)s1, 32, 64);
      union { uint32_t u[4]; short8 s8; } pu;
      pu.u[0] = hi ? r0 : a0;
      pu.u[1] = hi ? r1 : a1;
      pu.u[2] = hi ? b0 : r0;
      pu.u[3] = hi ? b1 : r1;
      int ch = (kst * 2 + u9) & 3;
#pragma unroll
      for (int ct = 0; ct < 8; ++ct) {
        short8 vf = *(const short8*)(vsb + (ct * 32 + lo) * 64 + ch * 16);
        Oa[ct] = __builtin_amdgcn_mfma_f32_32x32x16_bf16(vf, pu.s8, Oa[ct], 0, 0, 0);
      }
    }
    asm volatile("s_barrier" ::: "memory");              // readers done before restage
  }

  // l: lane pair holds complementary j halves
  l_ += __shfl_xor(l_, 32, 64);
  if (hi == 0)
    lrow[(size_t)jh * (Bn * Nn) + (size_t)b * Nn + i0 + w * 32 + lo] = l_;
  float invl = __builtin_amdgcn_rcpf(l_);
  __syncthreads();  // loop drained (vmcnt(0) at last iter); reuse all 64KB
#pragma unroll
  for (int ct = 0; ct < 8; ++ct)
#pragma unroll
    for (int g = 0; g < 4; ++g) {
      short4v pk;
#pragma unroll
      for (int r = 0; r < 4; ++r) pk[r] = (short)f2bf(Oa[ct][g * 4 + r] * invl);
      int chv = (ct * 4 + g + lo) & 31;
      *(short4v*)(smem + w * 16384 + lo * 512 + chv * 16 + hi * 8) = pk;
    }
  __syncthreads();
  u16* Opj = (jh == 0) ? Op0 : (jh == 1) ? Op1 : (jh == 2) ? Op2 : Op3;
  u16* Ob = Opj + ((size_t)b * Nn + i0 + w * 32) * (size_t)Cn;
#pragma unroll
  for (int s = 0; s < 16; ++s) {
    int rr = s * 2 + hi;
    short8 v8 = *(const short8*)(smem + w * 16384 + rr * 512 + lo * 16);
    int gc = (lo - rr) & 31;
    *(short8*)(Ob + (size_t)rr * Cn + gc * 8) = v8;
  }
}

// ---------------- combine the 4 KV partials -> OT (N,C) bf16 -----------------
__global__ void k_comb(const u16* __restrict__ O0, const u16* __restrict__ O1,
                       const u16* __restrict__ O2, const u16* __restrict__ O3,
                       const float* __restrict__ lrow, u16* __restrict__ OT) {
  int gid = blockIdx.x * 256 + threadIdx.x;  // 1M threads, 4 cols each
  int row = gid >> 6;
  int c4 = (gid & 63) << 2;
  float L = lrow[row] + lrow[Bn * Nn + row] + lrow[2 * Bn * Nn + row] + lrow[3 * Bn * Nn + row];
  float inv = __builtin_amdgcn_rcpf(L);
  size_t base = (size_t)row * Cn + c4;
  short4v a0 = *(const short4v*)(O0 + base);
  short4v a1 = *(const short4v*)(O1 + base);
  short4v a2 = *(const short4v*)(O2 + base);
  short4v a3 = *(const short4v*)(O3 + base);
  short4v o;
#pragma unroll
  for (int i = 0; i < 4; ++i)
    o[i] = (short)f2bf((b2f((u16)a0[i]) + b2f((u16)a1[i]) + b2f((u16)a2[i]) + b2f((u16)a3[i])) * inv);
  *(short4v*)(OT + base) = o;
}

// ---------------- proj GEMM + bias + residual --------------------------------
__global__ __launch_bounds__(256, 2)
void k_proj(const u16* __restrict__ wpb, const float* __restrict__ bp,
            const u16* __restrict__ OT, const float* __restrict__ x,
            float* __restrict__ out) {
  __shared__ __align__(16) char smem[65536];
  int tid = threadIdx.x, lane = tid & 63, w = tid >> 6, quad = lane >> 4, low = lane & 15;
  int n0 = blockIdx.x * 64, d0 = blockIdx.y * 64, b = blockIdx.z;
  {
    int r0 = w * 16;
#pragma unroll
    for (int s = 0; s < 8; ++s) {
      int rs = r0 + s * 2;
      int r = rs + (lane >> 5);
      int cb = (lane & 31) ^ (r & 7);
      gl_lds16(wpb + (size_t)(d0 + r) * Cn + cb * 8, smem + rs * 512);
      gl_lds16(OT + ((size_t)b * Nn + n0 + r) * Cn + cb * 8, smem + 32768 + rs * 512);
    }
  }
  asm volatile("s_waitcnt vmcnt(0)" ::: "memory");
  __syncthreads();
  f32x4 acc[4] = {{0.f,0.f,0.f,0.f},{0.f,0.f,0.f,0.f},{0.f,0.f,0.f,0.f},{0.f,0.f,0.f,0.f}};
#pragma unroll
  for (int kk = 0; kk < 8; ++kk) {
    short8 af = *(const short8*)(smem + sw512(w * 16 + low, kk * 4 + quad));
#pragma unroll
    for (int t = 0; t < 4; ++t) {
      short8 bf = *(const short8*)(smem + 32768 + sw512(t * 16 + low, kk * 4 + quad));
      acc[t] = __builtin_amdgcn_mfma_f32_16x16x32_bf16(af, bf, acc[t], 0, 0, 0);
    }
  }
  int dloc = d0 + w * 16 + quad * 4;
#pragma unroll
  for (int t = 0; t < 4; ++t)
#pragma unroll
    for (int r = 0; r < 4; ++r) {
      size_t idx = (size_t)b * Cn * Nn + (size_t)(dloc + r) * Nn + n0 + t * 16 + low;
      out[idx] = x[idx] + acc[t][r] + bp[dloc + r];
    }
}

// ---------------- launcher ----------------------------------------------------
extern "C" void kernel_launch(void* const* d_in, const int* in_sizes, int n_in,
                              void* d_out, int out_size, void* d_ws, size_t ws_size,
                              hipStream_t stream) {
  const float* x   = (const float*)d_in[0];
  const float* gsc = (const float*)d_in[1];
  const float* gbi = (const float*)d_in[2];
  const float* wq  = (const float*)d_in[3];
  const float* bq  = (const float*)d_in[4];
  const float* wk  = (const float*)d_in[5];
  const float* bk  = (const float*)d_in[6];
  const float* wv  = (const float*)d_in[7];
  const float* bv  = (const float*)d_in[8];
  const float* wp  = (const float*)d_in[9];
  const float* bp  = (const float*)d_in[10];
  float* out = (float*)d_out;

  char* ws = (char*)d_ws;
  u16*   wqkv  = (u16*)(ws + 0);          // 384 KB
  u16*   wpb   = (u16*)(ws + 393216);     // 128 KB
  float* bqkv  = (float*)(ws + 524288);   // 3 KB
  float* stats = (float*)(ws + 527360);   // 4 KB (per-part slots)
  float* lrow  = (float*)(ws + 532480);   // 256 KB
  u16*   hnT   = (u16*)(ws + 1048576);    // 8 MB; reused as Op0 after qkv
  u16*   qT    = (u16*)(ws + 9437184);    // 8 MB; reused as OT after flash
  u16*   kT    = (u16*)(ws + 17825792);   // 8 MB
  u16*   vv    = (u16*)(ws + 26214400);   // 8 MB
  u16*   Op1   = (u16*)(ws + 34603008);   // 8 MB
  u16*   Op2   = (u16*)(ws + 42991616);   // 8 MB
  u16*   Op3   = (u16*)(ws + 51380224);   // 8 MB; end ~57 MB

  k_cs<<<768, 256, 0, stream>>>(wq, wk, wv, wp, bq, bk, bv, x, wqkv, wpb, bqkv, stats);
  k_apply<<<dim3(64, 4), 256, 0, stream>>>(x, stats, gsc, gbi, hnT);
  k_qkv<<<dim3(16, 12, 4), 256, 0, stream>>>(wqkv, bqkv, hnT, qT, kT, vv);
  k_flash<<<dim3(32, 4, 4), 256, 0, stream>>>(qT, kT, vv, hnT /*Op0*/, Op1, Op2, Op3, lrow);
  k_comb<<<4096, 256, 0, stream>>>(hnT, Op1, Op2, Op3, lrow, qT /*OT*/);
  k_proj<<<dim3(64, 4, 4), 256, 0, stream>>>(wpb, bp, qT /*OT*/, x, out);
}